// Round 2
// baseline (235.301 us; speedup 1.0000x reference)
//
#include <hip/hip_runtime.h>
#include <hip/hip_bf16.h>

typedef __hip_bfloat16 bf16;
typedef short short8 __attribute__((ext_vector_type(8)));
typedef float floatx4 __attribute__((ext_vector_type(4)));

#define SZ (8192*192)   // one (B*L, C) fp32 plane in floats

__device__ __forceinline__ unsigned short f2b(float f) {
    unsigned u = __builtin_bit_cast(unsigned, f);
    u += 0x7FFFu + ((u >> 16) & 1u);   // RNE
    return (unsigned short)(u >> 16);
}
__device__ __forceinline__ float b2f(unsigned short h) {
    unsigned u = ((unsigned)h) << 16;
    return __builtin_bit_cast(float, u);
}
__device__ __forceinline__ unsigned pk2(float a, float b) {
    // packed bf16 pair (a in low half / lower address)
    return ((unsigned)f2b(b) << 16) | (unsigned)f2b(a);
}

// ---------------- dtype detect: bf16 vs fp32 inputs ----------------
__global__ void detect_kernel(const unsigned short* __restrict__ x16, int* __restrict__ flag) {
    __shared__ int cnt;
    if (threadIdx.x == 0) cnt = 0;
    __syncthreads();
    int c = 0;
    for (int i = threadIdx.x; i < 8192; i += 256) {
        int e = (x16[i] >> 7) & 0xFF;
        if (e >= 152) c++;
    }
    if (c) atomicAdd(&cnt, c);
    __syncthreads();
    if (threadIdx.x == 0) *flag = (cnt >= 32) ? 1 : 0;
}

// ---------------- fused weight transpose (->bf16 NxK) + small-vector cvt (->f32) ----------------
struct WPA { const void* s[11]; };
// s[]: w_qkv, w_proj, w_fc1, w_fc2, b_proj, g1, b1, g2, b2, b_fc1, b_fc2

__global__ __launch_bounds__(256) void wprep_kernel(WPA a, unsigned short* __restrict__ wdst,
                                                    float* __restrict__ vdst,
                                                    const int* __restrict__ flag) {
    int i = blockIdx.x * 256 + threadIdx.x;
    int f = *flag;
    if (i < 442368) {
        int seg, base, K, N;
        if (i < 110592)      { seg = 0; base = 0;      K = 192; N = 576; }
        else if (i < 147456) { seg = 1; base = 110592; K = 192; N = 192; }
        else if (i < 294912) { seg = 2; base = 147456; K = 192; N = 768; }
        else                 { seg = 3; base = 294912; K = 768; N = 192; }
        int j = i - base;
        int n = j / K, k = j - n * K;
        size_t src = (size_t)k * N + n;
        float v = f ? ((const float*)a.s[seg])[src] : b2f(((const unsigned short*)a.s[seg])[src]);
        wdst[i] = f2b(v);
    } else if (i < 444288) {
        int j = i - 442368;
        int seg, off;
        if (j < 960)       { seg = 4 + j / 192; off = j % 192; }
        else if (j < 1728) { seg = 9; off = j - 960; }
        else               { seg = 10; off = j - 1728; }
        float v = f ? ((const float*)a.s[seg])[off] : b2f(((const unsigned short*)a.s[seg])[off]);
        vdst[j] = v;
    }
}

// ---------------- prep: x (B,C,4096) -> xt=2x (B*L,C) f32 and img=LN bf16 ----------------
__global__ __launch_bounds__(256) void prep_kernel(const void* __restrict__ xin,
        const int* __restrict__ flag,
        const float* __restrict__ g1, const float* __restrict__ b1,
        float* __restrict__ xt, unsigned short* __restrict__ img) {
    __shared__ float tile[192][33];
    __shared__ float mu[32], rs[32];
    int tid = threadIdx.x;
    int t0 = blockIdx.x * 32;
    int b = t0 >> 12;
    int ts = t0 & 4095;
    int f = *flag;
    for (int idx = tid; idx < 192 * 32; idx += 256) {
        int c = idx >> 5, tt = idx & 31;
        int gi = ((b * 192 + c) << 12) + ts + tt;
        float raw = f ? ((const float*)xin)[gi] : b2f(((const unsigned short*)xin)[gi]);
        tile[c][tt] = 2.0f * raw;
    }
    __syncthreads();
    if (tid < 32) {
        float s = 0.f, sq = 0.f;
        for (int c = 0; c < 192; ++c) { float v = tile[c][tid]; s += v; sq += v * v; }
        float m = s * (1.0f / 192.0f);
        float var = sq * (1.0f / 192.0f) - m * m;
        mu[tid] = m;
        rs[tid] = rsqrtf(var + 1e-5f);
    }
    __syncthreads();
    for (int idx = tid; idx < 32 * 192; idx += 256) {
        int tt = idx / 192, c = idx % 192;
        float v = tile[c][tt];
        int o = (t0 + tt) * 192 + c;
        xt[o] = v;
        img[o] = f2b((v - mu[tt]) * rs[tt] * g1[c] + b1[c]);
    }
}

// ---------------- MFMA GEMM, TMx64 tile, LDS-free ----------------
// MODE 0: out bf16 = acc, q-cols (<192) pre-scaled by 1/sqrt(32)         (qkv)
// MODE 1: out f32  = acc + bias + resid                                  (proj, non-split fallback)
// MODE 2: out bf16 = gelu(acc + bias)                                    (fc1)
// MODE 4: A built on-the-fly from split-K attn partials (po,pl);
//         out f32 = acc + bias + resid                                   (proj + fused combine)
// MODE 5: out (transposed (B,C,4096), dtype per flag) = acc + bias + resid (fc2 + fused unprep)
template <int MODE, int TM>
__global__ __launch_bounds__(256) void mfma_gemm(const unsigned short* __restrict__ A,
        const float* __restrict__ pA, const float* __restrict__ pl,
        const unsigned short* __restrict__ WT, const float* __restrict__ bias,
        const float* __restrict__ resid, void* __restrict__ out,
        const int* __restrict__ flag, int N, int K) {
    int wave = threadIdx.x >> 6, lane = threadIdx.x & 63;
    int quad = lane >> 4, l16 = lane & 15;
    int m0 = blockIdx.x * TM, n0 = blockIdx.y * 64;
    constexpr int FH = TM / 64;            // fragment rows per wave / 16
    int arow = m0 + wave * (TM / 4) + l16;
    const unsigned short* ap = A + (size_t)arow * K + quad * 8;
    const unsigned short* wp = WT + (size_t)(n0 + l16) * K + quad * 8;
    floatx4 acc[FH][4] = {};
    float inv6[6];
    const float* prow0 = nullptr;
    if constexpr (MODE == 4) {
        prow0 = pA + (size_t)arow * 192;
        #pragma unroll
        for (int g = 0; g < 6; ++g)
            inv6[g] = 1.0f / (pl[(size_t)arow * 6 + g] + pl[(size_t)(8192 + arow) * 6 + g]);
    }
    #pragma unroll 2
    for (int kc = 0; kc < K; kc += 32) {
        short8 a0, a1;
        if constexpr (MODE == 4) {
            float iv = inv6[kc >> 5];
            const float* p0 = prow0 + kc + quad * 8;
            const float* p1 = p0 + (size_t)8192 * 192;
            #pragma unroll
            for (int j = 0; j < 8; ++j) a0[j] = (short)f2b((p0[j] + p1[j]) * iv);
        } else {
            a0 = *reinterpret_cast<const short8*>(ap + kc);
            if constexpr (FH == 2) a1 = *reinterpret_cast<const short8*>(ap + (size_t)16 * K + kc);
        }
        #pragma unroll
        for (int nt = 0; nt < 4; ++nt) {
            short8 w = *reinterpret_cast<const short8*>(wp + (size_t)nt * 16 * K + kc);
            acc[0][nt] = __builtin_amdgcn_mfma_f32_16x16x32_bf16(a0, w, acc[0][nt], 0, 0, 0);
            if constexpr (FH == 2)
                acc[1][nt] = __builtin_amdgcn_mfma_f32_16x16x32_bf16(a1, w, acc[1][nt], 0, 0, 0);
        }
    }
    int f = 0;
    if constexpr (MODE == 5) f = *flag;
    #pragma unroll
    for (int fh = 0; fh < FH; ++fh) {
        #pragma unroll
        for (int nt = 0; nt < 4; ++nt) {
            #pragma unroll
            for (int r = 0; r < 4; ++r) {
                int row = m0 + wave * (TM / 4) + fh * 16 + quad * 4 + r;
                int col = n0 + nt * 16 + l16;
                float v = acc[fh][nt][r];
                if (MODE == 0 && col < 192) v *= 0.17677669529663689f;
                if (MODE >= 1) v += bias[col];
                if (MODE == 2) v = 0.5f * v * (1.0f + erff(v * 0.70710678118654752f));
                if constexpr (MODE == 5) {
                    v += resid[(size_t)row * 192 + col];
                    int bb_ = row >> 12, t = row & 4095;
                    size_t o = ((size_t)(bb_ * 192 + col) << 12) + t;
                    if (f) ((float*)out)[o] = v;
                    else   ((unsigned short*)out)[o] = f2b(v);
                } else {
                    size_t o = (size_t)row * N + col;
                    if (MODE == 0 || MODE == 2) ((unsigned short*)out)[o] = f2b(v);
                    else                        ((float*)out)[o] = v + resid[o];
                }
            }
        }
    }
}

// ---------------- MFMA windowed attention (no-max softmax, permuted key axis) ----------------
// window shapes: br0=(16,16,4), br1=(16,4,16), br2=(4,16,16); S=1024, hd=32
__device__ __forceinline__ int tok_of(int br, int wb, int q) {
    if (br == 0) return ((q >> 6) << 8) | (((q >> 2) & 15) << 4) | (wb << 2) | (q & 3);
    else if (br == 1) return ((q >> 6) << 8) | (((wb << 2) + ((q >> 4) & 3)) << 4) | (q & 15);
    else return (((wb << 2) + (q >> 8)) << 8) | (q & 255);
}

// VT row address with octave offset (breaks the 8-row bank degeneracy)
__device__ __forceinline__ int vtaddr(int d) { return d * 72 + ((d >> 3) << 3); }

__device__ __forceinline__ const short8* kvptr(const unsigned short* __restrict__ qkv,
                                               int tb, int br, int wb, int q, int off) {
    int t = tok_of(br, wb, q);
    return reinterpret_cast<const short8*>(qkv + (size_t)(tb + t) * 576 + off);
}

// SPLIT=1: full 16 kt tiles per block, normalize + write attb bf16 (grid 768)
// SPLIT=2: 8 kt tiles per block, write f32 partial O (po) + partial denom (pl) (grid 1536)
template <int SPLIT>
__global__ __launch_bounds__(256) void attn_mfma(const unsigned short* __restrict__ qkv,
        unsigned short* __restrict__ attb, float* __restrict__ po, float* __restrict__ pl) {
    __shared__ __align__(16) unsigned short P[4][16 * 72];        // per-wave, rows=q, cols=pos(k)
    __shared__ __align__(16) unsigned short VT[2][32 * 72 + 32];  // double-buffered
    const int chunk = 96 * SPLIT;  // (768*SPLIT)/8, grid % 8 == 0 -> bijective
    int hw = blockIdx.x;
    int bid = (hw & 7) * chunk + (hw >> 3);
    int kh, rest;
    if (SPLIT == 2) { kh = bid & 1; rest = bid >> 1; }
    else            { kh = 0;       rest = bid; }
    int qt = rest & 15, head = (rest >> 4) & 1, wb = (rest >> 5) & 3, b = (rest >> 7) & 1, br = rest >> 8;
    int tid = threadIdx.x;
    int wave = tid >> 6, lane = tid & 63, quad = lane >> 4, l16 = lane & 15;
    int coff = br * 64 + head * 32;
    int tb = b << 12;
    // Q a-frag (q pre-scaled in qkv GEMM epilogue)
    int tq = tok_of(br, wb, qt * 64 + wave * 16 + l16);
    short8 aq = *reinterpret_cast<const short8*>(qkv + (size_t)(tb + tq) * 576 + coff + quad * 8);
    floatx4 o0 = {}, o1 = {};
    float lsum[4] = {0.f, 0.f, 0.f, 0.f};
    unsigned short* Pw = P[wave];
    int vkey5 = lane >> 2;           // within-wave key (0..15); global chunk key = wave*16+vkey5
    int vd = lane & 3;               // dim octave
    int vcol = 4 * vkey5 + wave;     // pos(key)

    const int NT = 16 / SPLIT;
    const int kt0 = kh * NT;

    // prefetch iteration 0's V + K fragments
    short8 vv, k0, k1, k2, k3;
    {
        int kc = kt0 * 64;
        vv = *kvptr(qkv, tb, br, wb, kc + wave * 16 + vkey5, 384 + coff + vd * 8);
        k0 = *kvptr(qkv, tb, br, wb, kc + l16,      192 + coff + quad * 8);
        k1 = *kvptr(qkv, tb, br, wb, kc + 16 + l16, 192 + coff + quad * 8);
        k2 = *kvptr(qkv, tb, br, wb, kc + 32 + l16, 192 + coff + quad * 8);
        k3 = *kvptr(qkv, tb, br, wb, kc + 48 + l16, 192 + coff + quad * 8);
    }

    for (int it = 0; it < NT; ++it) {
        unsigned short* VTb = VT[it & 1];
        // stage V^T for this iteration (buffer it&1 — its last readers finished
        // before the PREVIOUS barrier, so no pre-write barrier needed)
        #pragma unroll
        for (int j = 0; j < 8; ++j)
            VTb[vtaddr(vd * 8 + j) + vcol] = (unsigned short)vv[j];
        short8 ck0 = k0, ck1 = k1, ck2 = k2, ck3 = k3;
        // issue next iteration's global loads now; they stay outstanding across the
        // barrier and their latency hides under QK + exp + PV
        if (it + 1 < NT) {
            int kc = (kt0 + it + 1) * 64;
            vv = *kvptr(qkv, tb, br, wb, kc + wave * 16 + vkey5, 384 + coff + vd * 8);
            k0 = *kvptr(qkv, tb, br, wb, kc + l16,      192 + coff + quad * 8);
            k1 = *kvptr(qkv, tb, br, wb, kc + 16 + l16, 192 + coff + quad * 8);
            k2 = *kvptr(qkv, tb, br, wb, kc + 32 + l16, 192 + coff + quad * 8);
            k3 = *kvptr(qkv, tb, br, wb, kc + 48 + l16, 192 + coff + quad * 8);
        }
        __syncthreads();   // VT writes visible (single barrier per iteration)
        // S = Q K^T (4 tiles of 16 keys)
        floatx4 z = {};
        floatx4 s0 = __builtin_amdgcn_mfma_f32_16x16x32_bf16(aq, ck0, z, 0, 0, 0);
        floatx4 s1 = __builtin_amdgcn_mfma_f32_16x16x32_bf16(aq, ck1, z, 0, 0, 0);
        floatx4 s2 = __builtin_amdgcn_mfma_f32_16x16x32_bf16(aq, ck2, z, 0, 0, 0);
        floatx4 s3 = __builtin_amdgcn_mfma_f32_16x16x32_bf16(aq, ck3, z, 0, 0, 0);
        // exp (no max subtraction: |s|≲8 with LN'd inputs), P write as packed b64
        #pragma unroll
        for (int r = 0; r < 4; ++r) {
            float p0 = __expf(s0[r]);
            float p1 = __expf(s1[r]);
            float p2 = __expf(s2[r]);
            float p3 = __expf(s3[r]);
            lsum[r] += (p0 + p1) + (p2 + p3);
            uint2 w2; w2.x = pk2(p0, p1); w2.y = pk2(p2, p3);
            *reinterpret_cast<uint2*>(Pw + (quad * 4 + r) * 72 + 4 * l16) = w2;
        }
        // O += P V (per-wave P, shared VT)
        const unsigned short* pr = Pw + l16 * 72;
        short8 a0 = *reinterpret_cast<const short8*>(pr + quad * 8);
        short8 a1 = *reinterpret_cast<const short8*>(pr + 32 + quad * 8);
        const unsigned short* v0r = VTb + vtaddr(l16);
        const unsigned short* v1r = VTb + vtaddr(16 + l16);
        short8 b00 = *reinterpret_cast<const short8*>(v0r + quad * 8);
        short8 b01 = *reinterpret_cast<const short8*>(v0r + 32 + quad * 8);
        short8 b10 = *reinterpret_cast<const short8*>(v1r + quad * 8);
        short8 b11 = *reinterpret_cast<const short8*>(v1r + 32 + quad * 8);
        o0 = __builtin_amdgcn_mfma_f32_16x16x32_bf16(a0, b00, o0, 0, 0, 0);
        o0 = __builtin_amdgcn_mfma_f32_16x16x32_bf16(a1, b01, o0, 0, 0, 0);
        o1 = __builtin_amdgcn_mfma_f32_16x16x32_bf16(a0, b10, o1, 0, 0, 0);
        o1 = __builtin_amdgcn_mfma_f32_16x16x32_bf16(a1, b11, o1, 0, 0, 0);
    }
    // reduce softmax denominators within 16-lane groups
    #pragma unroll
    for (int r = 0; r < 4; ++r) {
        float ls = lsum[r];
        ls += __shfl_xor(ls, 1);
        ls += __shfl_xor(ls, 2);
        ls += __shfl_xor(ls, 4);
        ls += __shfl_xor(ls, 8);
        lsum[r] = ls;
    }
    if (SPLIT == 2) {
        // write f32 partials: O-half and denom-half are purely additive (no-max softmax)
        #pragma unroll
        for (int r = 0; r < 4; ++r) {
            int q = qt * 64 + wave * 16 + quad * 4 + r;
            int t = tok_of(br, wb, q);
            size_t o = ((size_t)(kh << 13) + tb + t) * 192 + coff;
            po[o + l16]      = o0[r];
            po[o + 16 + l16] = o1[r];
            if (l16 == 0) pl[(size_t)((kh << 13) + tb + t) * 6 + br * 2 + head] = lsum[r];
        }
    } else {
        #pragma unroll
        for (int r = 0; r < 4; ++r) {
            float inv = 1.0f / lsum[r];
            int q = qt * 64 + wave * 16 + quad * 4 + r;
            int t = tok_of(br, wb, q);
            size_t o = (size_t)(tb + t) * 192 + coff;
            attb[o + l16]      = f2b(o0[r] * inv);
            attb[o + 16 + l16] = f2b(o1[r] * inv);
        }
    }
}

// ---------------- LN over rows of (B*L, 192): f32 in -> bf16 out ----------------
__global__ __launch_bounds__(256) void ln_kernel(const float* __restrict__ in,
        const float* __restrict__ g, const float* __restrict__ bb, unsigned short* __restrict__ out) {
    int token = (blockIdx.x << 2) + (threadIdx.x >> 6);
    int lane = threadIdx.x & 63;
    const float* row = in + (size_t)token * 192;
    float v0 = row[lane], v1 = row[lane + 64], v2 = row[lane + 128];
    float s = v0 + v1 + v2, sq = v0 * v0 + v1 * v1 + v2 * v2;
    #pragma unroll
    for (int mask = 1; mask < 64; mask <<= 1) {
        s += __shfl_xor(s, mask);
        sq += __shfl_xor(sq, mask);
    }
    float m = s * (1.f / 192.f);
    float var = sq * (1.f / 192.f) - m * m;
    float rsd = rsqrtf(var + 1e-5f);
    unsigned short* orow = out + (size_t)token * 192;
    orow[lane]       = f2b((v0 - m) * rsd * g[lane]       + bb[lane]);
    orow[lane + 64]  = f2b((v1 - m) * rsd * g[lane + 64]  + bb[lane + 64]);
    orow[lane + 128] = f2b((v2 - m) * rsd * g[lane + 128] + bb[lane + 128]);
}

extern "C" void kernel_launch(void* const* d_in, const int* in_sizes, int n_in,
                              void* d_out, int out_size, void* d_ws, size_t ws_size,
                              hipStream_t stream) {
    float* ws = (float*)d_ws;

    // small fp32 vectors: b_proj, g1, b1, g2, b2, b_fc1, b_fc2 (1920 floats)
    float* vbase = ws;
    float* bprojf = vbase + 0;
    float* g1f    = vbase + 192;
    float* b1f    = vbase + 384;
    float* g2f    = vbase + 576;
    float* b2f    = vbase + 768;
    float* bfc1f  = vbase + 960;
    float* bfc2f  = vbase + 1728;

    // transposed bf16 weights (N x K), 442368 ushorts
    unsigned short* wbase = (unsigned short*)(ws + 1920);
    unsigned short* wqkvT = wbase + 0;
    unsigned short* wprojT = wbase + 110592;
    unsigned short* wfc1T = wbase + 147456;
    unsigned short* wfc2T = wbase + 294912;

    size_t p = 1920 + 442368 / 2;           // float offset after weights
    float* xt = ws + p; p += SZ;            // fp32 residual stream (xs)
    unsigned short* img = (unsigned short*)(ws + p); p += SZ / 2;   // bf16; also lnb
    size_t pQ = p;
    unsigned short* qkv = (unsigned short*)(ws + pQ);               // bf16 8192x576
    unsigned short* hbuf = (unsigned short*)(ws + pQ);              // bf16 8192x768 (aliases qkv)
    p = pQ + 8192 * 768 / 2;
    unsigned short* attb = (unsigned short*)(ws + p); p += SZ / 2;  // bf16 (fallback path only)
    int* flag = (int*)(ws + p); p += 16;
    // split-K attention partials (f32): 2 halves x (8192 x 192) O + (8192 x 6) denom
    float* po = ws + p; p += (size_t)2 * 8192 * 192;
    float* pl = ws + p; p += (size_t)2 * 8192 * 6;
    bool split_ok = ws_size >= p * sizeof(float);
    float* xs = xt;
    unsigned short* lnb = img;

    WPA wa;
    wa.s[0] = d_in[1];  wa.s[1] = d_in[2];  wa.s[2] = d_in[8];  wa.s[3] = d_in[10];
    wa.s[4] = d_in[3];  wa.s[5] = d_in[4];  wa.s[6] = d_in[5];  wa.s[7] = d_in[6];
    wa.s[8] = d_in[7];  wa.s[9] = d_in[9];  wa.s[10] = d_in[11];

    detect_kernel<<<dim3(1), dim3(256), 0, stream>>>((const unsigned short*)d_in[0], flag);
    wprep_kernel<<<dim3(1736), dim3(256), 0, stream>>>(wa, wbase, vbase, flag);
    prep_kernel<<<dim3(256), dim3(256), 0, stream>>>(d_in[0], flag, g1f, b1f, xt, img);
    mfma_gemm<0, 64><<<dim3(128, 9), dim3(256), 0, stream>>>(
        img, nullptr, nullptr, wqkvT, nullptr, nullptr, qkv, nullptr, 576, 192);
    if (split_ok) {
        attn_mfma<2><<<dim3(1536), dim3(256), 0, stream>>>(qkv, nullptr, po, pl);
        // proj with fused split-combine: A = (po0+po1) * 1/(pl0+pl1) on the fly
        mfma_gemm<4, 64><<<dim3(128, 3), dim3(256), 0, stream>>>(
            (const unsigned short*)po, po, pl, wprojT, bprojf, xt, xs, nullptr, 192, 192);
    } else {
        attn_mfma<1><<<dim3(768), dim3(256), 0, stream>>>(qkv, attb, nullptr, nullptr);
        mfma_gemm<1, 64><<<dim3(128, 3), dim3(256), 0, stream>>>(
            attb, nullptr, nullptr, wprojT, bprojf, xt, xs, nullptr, 192, 192);
    }
    ln_kernel<<<dim3(2048), dim3(256), 0, stream>>>(xs, g2f, b2f, lnb);
    mfma_gemm<2, 64><<<dim3(128, 12), dim3(256), 0, stream>>>(
        lnb, nullptr, nullptr, wfc1T, bfc1f, nullptr, hbuf, nullptr, 768, 192);
    // fc2 with fused transpose-output (writes d_out directly, dtype per flag)
    mfma_gemm<5, 64><<<dim3(128, 3), dim3(256), 0, stream>>>(
        hbuf, nullptr, nullptr, wfc2T, bfc2f, xs, d_out, flag, 192, 768);
}

// Round 4
// 206.067 us; speedup vs baseline: 1.1419x; 1.1419x over previous
//
#include <hip/hip_runtime.h>
#include <hip/hip_bf16.h>

typedef __hip_bfloat16 bf16;
typedef short short8 __attribute__((ext_vector_type(8)));
typedef float floatx4 __attribute__((ext_vector_type(4)));

#define SZ (8192*192)   // one (B*L, C) fp32 plane in floats

__device__ __forceinline__ unsigned short f2b(float f) {
    unsigned u = __builtin_bit_cast(unsigned, f);
    u += 0x7FFFu + ((u >> 16) & 1u);   // RNE
    return (unsigned short)(u >> 16);
}
__device__ __forceinline__ float b2f(unsigned short h) {
    unsigned u = ((unsigned)h) << 16;
    return __builtin_bit_cast(float, u);
}
__device__ __forceinline__ unsigned pk2(float a, float b) {
    // packed bf16 pair (a in low half / lower address)
    return ((unsigned)f2b(b) << 16) | (unsigned)f2b(a);
}

// ---------------- dtype detect: bf16 vs fp32 inputs ----------------
__global__ void detect_kernel(const unsigned short* __restrict__ x16, int* __restrict__ flag) {
    __shared__ int cnt;
    if (threadIdx.x == 0) cnt = 0;
    __syncthreads();
    int c = 0;
    for (int i = threadIdx.x; i < 8192; i += 256) {
        int e = (x16[i] >> 7) & 0xFF;
        if (e >= 152) c++;
    }
    if (c) atomicAdd(&cnt, c);
    __syncthreads();
    if (threadIdx.x == 0) *flag = (cnt >= 32) ? 1 : 0;
}

// ---------------- fused weight transpose (->bf16 NxK) + small-vector cvt (->f32) ----------------
struct WPA { const void* s[11]; };
// s[]: w_qkv, w_proj, w_fc1, w_fc2, b_proj, g1, b1, g2, b2, b_fc1, b_fc2

__global__ __launch_bounds__(256) void wprep_kernel(WPA a, unsigned short* __restrict__ wdst,
                                                    float* __restrict__ vdst,
                                                    const int* __restrict__ flag) {
    int i = blockIdx.x * 256 + threadIdx.x;
    int f = *flag;
    if (i < 442368) {
        int seg, base, K, N;
        if (i < 110592)      { seg = 0; base = 0;      K = 192; N = 576; }
        else if (i < 147456) { seg = 1; base = 110592; K = 192; N = 192; }
        else if (i < 294912) { seg = 2; base = 147456; K = 192; N = 768; }
        else                 { seg = 3; base = 294912; K = 768; N = 192; }
        int j = i - base;
        int n = j / K, k = j - n * K;
        size_t src = (size_t)k * N + n;
        float v = f ? ((const float*)a.s[seg])[src] : b2f(((const unsigned short*)a.s[seg])[src]);
        wdst[i] = f2b(v);
    } else if (i < 444288) {
        int j = i - 442368;
        int seg, off;
        if (j < 960)       { seg = 4 + j / 192; off = j % 192; }
        else if (j < 1728) { seg = 9; off = j - 960; }
        else               { seg = 10; off = j - 1728; }
        float v = f ? ((const float*)a.s[seg])[off] : b2f(((const unsigned short*)a.s[seg])[off]);
        vdst[j] = v;
    }
}

// ---------------- prep: x (B,C,4096) -> xt=2x (B*L,C) f32 and img=LN bf16 ----------------
__global__ __launch_bounds__(256) void prep_kernel(const void* __restrict__ xin,
        const int* __restrict__ flag,
        const float* __restrict__ g1, const float* __restrict__ b1,
        float* __restrict__ xt, unsigned short* __restrict__ img) {
    __shared__ float tile[192][33];
    __shared__ float mu[32], rs[32];
    int tid = threadIdx.x;
    int t0 = blockIdx.x * 32;
    int b = t0 >> 12;
    int ts = t0 & 4095;
    int f = *flag;
    for (int idx = tid; idx < 192 * 32; idx += 256) {
        int c = idx >> 5, tt = idx & 31;
        int gi = ((b * 192 + c) << 12) + ts + tt;
        float raw = f ? ((const float*)xin)[gi] : b2f(((const unsigned short*)xin)[gi]);
        tile[c][tt] = 2.0f * raw;
    }
    __syncthreads();
    {
        // 8 threads per token, 24 channels each, then 3-step shfl reduce within the 8-lane group
        int tt = tid >> 3, j = tid & 7;
        int c0 = j * 24;
        float s = 0.f, sq = 0.f;
        #pragma unroll
        for (int i = 0; i < 24; ++i) { float v = tile[c0 + i][tt]; s += v; sq += v * v; }
        s += __shfl_xor(s, 1); sq += __shfl_xor(sq, 1);
        s += __shfl_xor(s, 2); sq += __shfl_xor(sq, 2);
        s += __shfl_xor(s, 4); sq += __shfl_xor(sq, 4);
        if (j == 0) {
            float m = s * (1.0f / 192.0f);
            float var = sq * (1.0f / 192.0f) - m * m;
            mu[tt] = m;
            rs[tt] = rsqrtf(var + 1e-5f);
        }
    }
    __syncthreads();
    for (int idx = tid; idx < 32 * 192; idx += 256) {
        int tt = idx / 192, c = idx % 192;
        float v = tile[c][tt];
        int o = (t0 + tt) * 192 + c;
        xt[o] = v;
        img[o] = f2b((v - mu[tt]) * rs[tt] * g1[c] + b1[c]);
    }
}

// ---------------- MFMA GEMM, per-wave 32x64 tile (FH=2), W waves/block ----------------
// MODE 0: out bf16 = acc, q-cols (<192) pre-scaled by 1/sqrt(32)   (qkv)
// MODE 1: out f32  = acc + bias + resid                            (proj)
// MODE 2: out bf16 = gelu(acc + bias)                              (fc1)
// MODE 3: out f32  = acc + bias + resid (in-place resid==out ok)   (fc2)
template <int MODE, int W>
__global__ __launch_bounds__(64 * W) void mfma_gemm(const unsigned short* __restrict__ A,
        const unsigned short* __restrict__ WT, const float* __restrict__ bias,
        const float* __restrict__ resid, void* __restrict__ out, int N, int K) {
    int wave = threadIdx.x >> 6, lane = threadIdx.x & 63;
    int quad = lane >> 4, l16 = lane & 15;
    int m0 = blockIdx.x * (32 * W) + wave * 32, n0 = blockIdx.y * 64;
    const unsigned short* ap = A + (size_t)(m0 + l16) * K + quad * 8;
    const unsigned short* wp = WT + (size_t)(n0 + l16) * K + quad * 8;
    floatx4 acc[2][4] = {};
    #pragma unroll 2
    for (int kc = 0; kc < K; kc += 32) {
        short8 a0 = *reinterpret_cast<const short8*>(ap + kc);
        short8 a1 = *reinterpret_cast<const short8*>(ap + (size_t)16 * K + kc);
        #pragma unroll
        for (int nt = 0; nt < 4; ++nt) {
            short8 w = *reinterpret_cast<const short8*>(wp + (size_t)nt * 16 * K + kc);
            acc[0][nt] = __builtin_amdgcn_mfma_f32_16x16x32_bf16(a0, w, acc[0][nt], 0, 0, 0);
            acc[1][nt] = __builtin_amdgcn_mfma_f32_16x16x32_bf16(a1, w, acc[1][nt], 0, 0, 0);
        }
    }
    #pragma unroll
    for (int fh = 0; fh < 2; ++fh) {
        #pragma unroll
        for (int nt = 0; nt < 4; ++nt) {
            #pragma unroll
            for (int r = 0; r < 4; ++r) {
                int row = m0 + fh * 16 + quad * 4 + r;
                int col = n0 + nt * 16 + l16;
                float v = acc[fh][nt][r];
                if (MODE == 0 && col < 192) v *= 0.17677669529663689f;
                if (MODE >= 1) v += bias[col];
                if (MODE == 2) v = 0.5f * v * (1.0f + erff(v * 0.70710678118654752f));
                size_t o = (size_t)row * N + col;
                if (MODE == 0 || MODE == 2) ((unsigned short*)out)[o] = f2b(v);
                else                        ((float*)out)[o] = v + resid[o];
            }
        }
    }
}

// ---------------- MFMA windowed attention (no-max softmax, permuted key axis) ----------------
// window shapes: br0=(16,16,4), br1=(16,4,16), br2=(4,16,16); S=1024, hd=32
__device__ __forceinline__ int tok_of(int br, int wb, int q) {
    if (br == 0) return ((q >> 6) << 8) | (((q >> 2) & 15) << 4) | (wb << 2) | (q & 3);
    else if (br == 1) return ((q >> 6) << 8) | (((wb << 2) + ((q >> 4) & 3)) << 4) | (q & 15);
    else return (((wb << 2) + (q >> 8)) << 8) | (q & 255);
}

// VT row address with octave offset (breaks the 8-row bank degeneracy)
__device__ __forceinline__ int vtaddr(int d) { return d * 72 + ((d >> 3) << 3); }

// SPLIT=1: full 16 kt tiles per block, normalize + write attb bf16 (grid 768)
// SPLIT=2: 8 kt tiles per block, write f32 partial O (po) + partial denom (pl) (grid 1536)
// K/V fragment addresses are affine in the tile index for every branch
// (t = t_base + 256*kt for br0/br1, t_base + 64*kt for br2) -> pointer-stepped loads.
template <int SPLIT>
__global__ __launch_bounds__(256) void attn_mfma(const unsigned short* __restrict__ qkv,
        unsigned short* __restrict__ attb, float* __restrict__ po, float* __restrict__ pl) {
    __shared__ __align__(16) unsigned short P[4][16 * 72];        // per-wave, rows=q, cols=pos(k)
    __shared__ __align__(16) unsigned short VT[2][32 * 72 + 32];  // double-buffered
    const int chunk = 96 * SPLIT;  // (768*SPLIT)/8, grid % 8 == 0 -> bijective
    int hw = blockIdx.x;
    int bid = (hw & 7) * chunk + (hw >> 3);
    int kh, rest;
    if (SPLIT == 2) { kh = bid & 1; rest = bid >> 1; }
    else            { kh = 0;       rest = bid; }
    int qt = rest & 15, head = (rest >> 4) & 1, wb = (rest >> 5) & 3, b = (rest >> 7) & 1, br = rest >> 8;
    int tid = threadIdx.x;
    int wave = tid >> 6, lane = tid & 63, quad = lane >> 4, l16 = lane & 15;
    int coff = br * 64 + head * 32;
    int tb = b << 12;
    // Q a-frag (q pre-scaled in qkv GEMM epilogue)
    int tq = tok_of(br, wb, qt * 64 + wave * 16 + l16);
    short8 aq = *reinterpret_cast<const short8*>(qkv + (size_t)(tb + tq) * 576 + coff + quad * 8);
    floatx4 o0 = {}, o1 = {};
    float lsum[4] = {0.f, 0.f, 0.f, 0.f};
    unsigned short* Pw = P[wave];
    int vkey5 = lane >> 2;           // within-wave key (0..15); global chunk key = wave*16+vkey5
    int vd = lane & 3;               // dim octave
    int vcol = 4 * vkey5 + wave;     // pos(key)

    const int NT = 16 / SPLIT;
    const int kt0 = kh * NT;
    const int kc0 = kt0 * 64;
    const size_t stp = (size_t)((br == 2) ? 64 : 256) * 576;  // token step per kt, in ushorts

    // base pointers for iteration kt0's fragments; advance by stp each iteration
    const unsigned short* vp  = qkv + (size_t)(tb + tok_of(br, wb, kc0 + wave * 16 + vkey5)) * 576 + 384 + coff + vd * 8;
    const unsigned short* kpA = qkv + (size_t)(tb + tok_of(br, wb, kc0 + l16))      * 576 + 192 + coff + quad * 8;
    const unsigned short* kpB = qkv + (size_t)(tb + tok_of(br, wb, kc0 + 16 + l16)) * 576 + 192 + coff + quad * 8;
    const unsigned short* kpC = qkv + (size_t)(tb + tok_of(br, wb, kc0 + 32 + l16)) * 576 + 192 + coff + quad * 8;
    const unsigned short* kpD = qkv + (size_t)(tb + tok_of(br, wb, kc0 + 48 + l16)) * 576 + 192 + coff + quad * 8;

    short8 vv = *reinterpret_cast<const short8*>(vp);
    short8 k0 = *reinterpret_cast<const short8*>(kpA);
    short8 k1 = *reinterpret_cast<const short8*>(kpB);
    short8 k2 = *reinterpret_cast<const short8*>(kpC);
    short8 k3 = *reinterpret_cast<const short8*>(kpD);

    for (int it = 0; it < NT; ++it) {
        unsigned short* VTb = VT[it & 1];
        // stage V^T for this iteration (buffer it&1 — its last readers finished
        // before the PREVIOUS barrier, so no pre-write barrier needed)
        #pragma unroll
        for (int j = 0; j < 8; ++j)
            VTb[vtaddr(vd * 8 + j) + vcol] = (unsigned short)vv[j];
        short8 ck0 = k0, ck1 = k1, ck2 = k2, ck3 = k3;
        // issue next iteration's global loads now; they stay outstanding across the
        // barrier and their latency hides under QK + exp + PV
        if (it + 1 < NT) {
            vp += stp; kpA += stp; kpB += stp; kpC += stp; kpD += stp;
            vv = *reinterpret_cast<const short8*>(vp);
            k0 = *reinterpret_cast<const short8*>(kpA);
            k1 = *reinterpret_cast<const short8*>(kpB);
            k2 = *reinterpret_cast<const short8*>(kpC);
            k3 = *reinterpret_cast<const short8*>(kpD);
        }
        __syncthreads();   // VT writes visible (single barrier per iteration)
        // S = Q K^T (4 tiles of 16 keys)
        floatx4 z = {};
        floatx4 s0 = __builtin_amdgcn_mfma_f32_16x16x32_bf16(aq, ck0, z, 0, 0, 0);
        floatx4 s1 = __builtin_amdgcn_mfma_f32_16x16x32_bf16(aq, ck1, z, 0, 0, 0);
        floatx4 s2 = __builtin_amdgcn_mfma_f32_16x16x32_bf16(aq, ck2, z, 0, 0, 0);
        floatx4 s3 = __builtin_amdgcn_mfma_f32_16x16x32_bf16(aq, ck3, z, 0, 0, 0);
        // exp (no max subtraction: |s|≲8 with LN'd inputs), P write as packed b64
        #pragma unroll
        for (int r = 0; r < 4; ++r) {
            float p0 = __expf(s0[r]);
            float p1 = __expf(s1[r]);
            float p2 = __expf(s2[r]);
            float p3 = __expf(s3[r]);
            lsum[r] += (p0 + p1) + (p2 + p3);
            uint2 w2; w2.x = pk2(p0, p1); w2.y = pk2(p2, p3);
            *reinterpret_cast<uint2*>(Pw + (quad * 4 + r) * 72 + 4 * l16) = w2;
        }
        // O += P V (per-wave P, shared VT)
        const unsigned short* pr = Pw + l16 * 72;
        short8 a0 = *reinterpret_cast<const short8*>(pr + quad * 8);
        short8 a1 = *reinterpret_cast<const short8*>(pr + 32 + quad * 8);
        const unsigned short* v0r = VTb + vtaddr(l16);
        const unsigned short* v1r = VTb + vtaddr(16 + l16);
        short8 b00 = *reinterpret_cast<const short8*>(v0r + quad * 8);
        short8 b01 = *reinterpret_cast<const short8*>(v0r + 32 + quad * 8);
        short8 b10 = *reinterpret_cast<const short8*>(v1r + quad * 8);
        short8 b11 = *reinterpret_cast<const short8*>(v1r + 32 + quad * 8);
        o0 = __builtin_amdgcn_mfma_f32_16x16x32_bf16(a0, b00, o0, 0, 0, 0);
        o0 = __builtin_amdgcn_mfma_f32_16x16x32_bf16(a1, b01, o0, 0, 0, 0);
        o1 = __builtin_amdgcn_mfma_f32_16x16x32_bf16(a0, b10, o1, 0, 0, 0);
        o1 = __builtin_amdgcn_mfma_f32_16x16x32_bf16(a1, b11, o1, 0, 0, 0);
    }
    // reduce softmax denominators within 16-lane groups
    #pragma unroll
    for (int r = 0; r < 4; ++r) {
        float ls = lsum[r];
        ls += __shfl_xor(ls, 1);
        ls += __shfl_xor(ls, 2);
        ls += __shfl_xor(ls, 4);
        ls += __shfl_xor(ls, 8);
        lsum[r] = ls;
    }
    if (SPLIT == 2) {
        // write f32 partials: O-half and denom-half are purely additive (no-max softmax)
        #pragma unroll
        for (int r = 0; r < 4; ++r) {
            int q = qt * 64 + wave * 16 + quad * 4 + r;
            int t = tok_of(br, wb, q);
            size_t o = ((size_t)(kh << 13) + tb + t) * 192 + coff;
            po[o + l16]      = o0[r];
            po[o + 16 + l16] = o1[r];
            if (l16 == 0) pl[(size_t)((kh << 13) + tb + t) * 6 + br * 2 + head] = lsum[r];
        }
    } else {
        #pragma unroll
        for (int r = 0; r < 4; ++r) {
            float inv = 1.0f / lsum[r];
            int q = qt * 64 + wave * 16 + quad * 4 + r;
            int t = tok_of(br, wb, q);
            size_t o = (size_t)(tb + t) * 192 + coff;
            attb[o + l16]      = f2b(o0[r] * inv);
            attb[o + 16 + l16] = f2b(o1[r] * inv);
        }
    }
}

// combine split-K halves: attb = (po0 + po1) / (pl0 + pl1), bf16
__global__ __launch_bounds__(256) void attn_combine(const float* __restrict__ po,
        const float* __restrict__ pl, unsigned short* __restrict__ attb) {
    int token = (blockIdx.x << 2) + (threadIdx.x >> 6);
    int lane = threadIdx.x & 63;
    const float* r0 = po + (size_t)token * 192;
    const float* r1 = r0 + (size_t)8192 * 192;
    const float* q0 = pl + (size_t)token * 6;
    const float* q1 = q0 + (size_t)8192 * 6;
    unsigned short* orow = attb + (size_t)token * 192;
    #pragma unroll
    for (int sgm = 0; sgm < 3; ++sgm) {
        int d = lane + sgm * 64;
        int g = d >> 5;                       // br*2 + head
        float denom = q0[g] + q1[g];
        orow[d] = f2b((r0[d] + r1[d]) / denom);
    }
}

// ---------------- LN over rows of (B*L, 192): f32 in -> bf16 out ----------------
__global__ __launch_bounds__(256) void ln_kernel(const float* __restrict__ in,
        const float* __restrict__ g, const float* __restrict__ bb, unsigned short* __restrict__ out) {
    int token = (blockIdx.x << 2) + (threadIdx.x >> 6);
    int lane = threadIdx.x & 63;
    const float* row = in + (size_t)token * 192;
    float v0 = row[lane], v1 = row[lane + 64], v2 = row[lane + 128];
    float s = v0 + v1 + v2, sq = v0 * v0 + v1 * v1 + v2 * v2;
    #pragma unroll
    for (int mask = 1; mask < 64; mask <<= 1) {
        s += __shfl_xor(s, mask);
        sq += __shfl_xor(sq, mask);
    }
    float m = s * (1.f / 192.f);
    float var = sq * (1.f / 192.f) - m * m;
    float rsd = rsqrtf(var + 1e-5f);
    unsigned short* orow = out + (size_t)token * 192;
    orow[lane]       = f2b((v0 - m) * rsd * g[lane]       + bb[lane]);
    orow[lane + 64]  = f2b((v1 - m) * rsd * g[lane + 64]  + bb[lane + 64]);
    orow[lane + 128] = f2b((v2 - m) * rsd * g[lane + 128] + bb[lane + 128]);
}

// ---------------- final transpose (B*L,C) f32 -> (B,C,4096) out dtype per flag ----------------
__global__ __launch_bounds__(256) void unprep_kernel(const float* __restrict__ xs,
                                                     void* __restrict__ out,
                                                     const int* __restrict__ flag) {
    __shared__ float tile[192][33];
    int tid = threadIdx.x;
    int t0 = blockIdx.x * 32;
    int b = t0 >> 12, ts = t0 & 4095;
    for (int idx = tid; idx < 32 * 192; idx += 256) {
        int tt = idx / 192, c = idx % 192;
        tile[c][tt] = xs[(size_t)(t0 + tt) * 192 + c];
    }
    __syncthreads();
    int f = *flag;
    for (int idx = tid; idx < 192 * 32; idx += 256) {
        int c = idx >> 5, tt = idx & 31;
        float v = tile[c][tt];
        int o = ((b * 192 + c) << 12) + ts + tt;
        if (f) ((float*)out)[o] = v;
        else   ((unsigned short*)out)[o] = f2b(v);
    }
}

extern "C" void kernel_launch(void* const* d_in, const int* in_sizes, int n_in,
                              void* d_out, int out_size, void* d_ws, size_t ws_size,
                              hipStream_t stream) {
    float* ws = (float*)d_ws;

    // small fp32 vectors: b_proj, g1, b1, g2, b2, b_fc1, b_fc2 (1920 floats)
    float* vbase = ws;
    float* bprojf = vbase + 0;
    float* g1f    = vbase + 192;
    float* b1f    = vbase + 384;
    float* g2f    = vbase + 576;
    float* b2f    = vbase + 768;
    float* bfc1f  = vbase + 960;
    float* bfc2f  = vbase + 1728;

    // transposed bf16 weights (N x K), 442368 ushorts
    unsigned short* wbase = (unsigned short*)(ws + 1920);
    unsigned short* wqkvT = wbase + 0;
    unsigned short* wprojT = wbase + 110592;
    unsigned short* wfc1T = wbase + 147456;
    unsigned short* wfc2T = wbase + 294912;

    size_t p = 1920 + 442368 / 2;           // float offset after weights
    float* xt = ws + p; p += SZ;            // fp32 residual stream (xs)
    unsigned short* img = (unsigned short*)(ws + p); p += SZ / 2;   // bf16; also lnb
    size_t pQ = p;
    unsigned short* qkv = (unsigned short*)(ws + pQ);               // bf16 8192x576
    unsigned short* hbuf = (unsigned short*)(ws + pQ);              // bf16 8192x768 (aliases qkv)
    p = pQ + 8192 * 768 / 2;
    unsigned short* attb = (unsigned short*)(ws + p); p += SZ / 2;  // bf16
    int* flag = (int*)(ws + p); p += 16;
    // split-K attention partials (f32): 2 halves x (8192 x 192) O + (8192 x 6) denom
    float* po = ws + p; p += (size_t)2 * 8192 * 192;
    float* pl = ws + p; p += (size_t)2 * 8192 * 6;
    bool split_ok = ws_size >= p * sizeof(float);
    float* xs = xt;
    unsigned short* lnb = img;

    WPA wa;
    wa.s[0] = d_in[1];  wa.s[1] = d_in[2];  wa.s[2] = d_in[8];  wa.s[3] = d_in[10];
    wa.s[4] = d_in[3];  wa.s[5] = d_in[4];  wa.s[6] = d_in[5];  wa.s[7] = d_in[6];
    wa.s[8] = d_in[7];  wa.s[9] = d_in[9];  wa.s[10] = d_in[11];

    detect_kernel<<<dim3(1), dim3(256), 0, stream>>>((const unsigned short*)d_in[0], flag);
    wprep_kernel<<<dim3(1736), dim3(256), 0, stream>>>(wa, wbase, vbase, flag);
    prep_kernel<<<dim3(256), dim3(256), 0, stream>>>(d_in[0], flag, g1f, b1f, xt, img);
    // qkv: 2-wave blocks (1152 blocks, 4.5/CU)
    mfma_gemm<0, 2><<<dim3(128, 9), dim3(128), 0, stream>>>(
        img, wqkvT, nullptr, nullptr, qkv, 576, 192);
    if (split_ok) {
        attn_mfma<2><<<dim3(1536), dim3(256), 0, stream>>>(qkv, nullptr, po, pl);
        attn_combine<<<dim3(2048), dim3(256), 0, stream>>>(po, pl, attb);
    } else {
        attn_mfma<1><<<dim3(768), dim3(256), 0, stream>>>(qkv, attb, nullptr, nullptr);
    }
    // proj: 1-wave blocks (768 blocks, 3/CU — every CU busy)
    mfma_gemm<1, 1><<<dim3(256, 3), dim3(64), 0, stream>>>(
        attb, wprojT, bprojf, xt, xs, 192, 192);
    ln_kernel<<<dim3(2048), dim3(256), 0, stream>>>(xs, g2f, b2f, lnb);
    // fc1: 2-wave blocks (1536 blocks, 6/CU)
    mfma_gemm<2, 2><<<dim3(128, 12), dim3(128), 0, stream>>>(
        lnb, wfc1T, bfc1f, nullptr, hbuf, 768, 192);
    // fc2: 1-wave blocks (768 blocks, 3/CU)
    mfma_gemm<3, 1><<<dim3(256, 3), dim3(64), 0, stream>>>(
        hbuf, wfc2T, bfc2f, xs, xs, 192, 768);
    unprep_kernel<<<dim3(256), dim3(256), 0, stream>>>(xs, d_out, flag);
}